// Round 3
// baseline (399.770 us; speedup 1.0000x reference)
//
#include <hip/hip_runtime.h>

#define MIN_VAL 1e-8f
#define SENT    1e10f   // sentinel for invalid targets: d ~ 1e20 dominates all valid
#define ACCINIT 1e30f

constexpr int P     = 256;   // bins per sample (bins input is [N, P+1])
constexpr int BLOCK = 256;
constexpr int CHUNK = 512;   // targets per block
constexpr int COLSTRIDE = CHUNK + 16;  // padded to kill write bank conflicts

// ---------------------------------------------------------------------------
// ws layout (poisoned 0xAA before every launch; memsets re-init every call):
//   [0,4)    : unsigned done          (memset 0x00)
//   [64,128) : double ysum[8]         (memset 0x00)
//   [128,160): unsigned ycnt[8]       (memset 0x00)
//   [192, 192+N*P*4): unsigned minbits[N*P]  (memset 0xFF = UINT_MAX)
// ---------------------------------------------------------------------------

__global__ void __launch_bounds__(BLOCK)
chamfer_main(const float* __restrict__ bins, const float* __restrict__ tgt,
             int N, int M, unsigned* done, double* ysum, unsigned* ycnt,
             unsigned* minbits, float* out) {
    const int n   = blockIdx.y;
    const int m0  = blockIdx.x * CHUNK;
    const int tid = threadIdx.x;
    const int tg  = tid & 15;   // position within 16-lane bin-group
    const int bg  = tid >> 4;   // bin group: bins [bg*16, bg*16+16)

    __shared__ float  s_bc[P];
    __shared__ float  s_t[CHUNK];
    __shared__ float  s_col[16 * COLSTRIDE];  // [bg][target] partial col-mins
    __shared__ double s_ws[BLOCK / 64];
    __shared__ unsigned s_wc[BLOCK / 64];
    __shared__ int s_last;

    // ---- stage bins (thread tid -> bin tid) -------------------------------
    const float* bn = bins + (size_t)n * (P + 1);
    s_bc[tid] = 0.5f * (bn[tid] + bn[tid + 1]);

    // ---- stage targets (thread owns g = tid and g = tid+256) --------------
    const float* tp = tgt + (size_t)n * M + m0;
    float ta = (m0 + tid < M)       ? tp[tid]       : -1.0f;
    float tb = (m0 + tid + 256 < M) ? tp[tid + 256] : -1.0f;
    bool va = ta >= MIN_VAL, vb = tb >= MIN_VAL;
    s_t[tid]       = va ? ta : SENT;
    s_t[tid + 256] = vb ? tb : SENT;
    __syncthreads();

    // ---- load register tile: 16 bins x 32 targets -------------------------
    float bcv[16];
#pragma unroll
    for (int i = 0; i < 16; i += 4) {
        float4 v = *(const float4*)&s_bc[bg * 16 + i];
        bcv[i] = v.x; bcv[i + 1] = v.y; bcv[i + 2] = v.z; bcv[i + 3] = v.w;
    }
    float tv[32];
#pragma unroll
    for (int j = 0; j < 32; ++j) tv[j] = s_t[j * 16 + tg];  // interleaved ownership

    float rmin[16], cmin[32];
#pragma unroll
    for (int i = 0; i < 16; ++i) rmin[i] = ACCINIT;
#pragma unroll
    for (int j = 0; j < 32; ++j) cmin[j] = ACCINIT;

    // ---- 512 pairs: d = (bc - t)^2, accumulate both min directions --------
#pragma unroll
    for (int j = 0; j < 32; ++j) {
        float t = tv[j];
        float cm = cmin[j];
#pragma unroll
        for (int i = 0; i < 16; ++i) {
            float d = bcv[i] - t;
            d = d * d;
            rmin[i] = fminf(rmin[i], d);
            cm = fminf(cm, d);
        }
        cmin[j] = cm;
    }

    // ---- row (per-bin) combine: shfl across the 16-lane bin-group ---------
#pragma unroll
    for (int i = 0; i < 16; ++i) {
        float r = rmin[i];
        r = fminf(r, __shfl_down(r, 8, 16));
        r = fminf(r, __shfl_down(r, 4, 16));
        r = fminf(r, __shfl_down(r, 2, 16));
        r = fminf(r, __shfl_down(r, 1, 16));
        rmin[i] = r;
    }
    if (tg == 0) {
#pragma unroll
        for (int i = 0; i < 16; ++i)
            atomicMin(&minbits[n * P + bg * 16 + i], __float_as_uint(rmin[i]));
    }

    // ---- col (per-target) combine via LDS ---------------------------------
#pragma unroll
    for (int j = 0; j < 32; ++j)
        s_col[bg * COLSTRIDE + j * 16 + tg] = cmin[j];
    __syncthreads();

    float c0 = s_col[tid];        // target g = tid
    float c1 = s_col[tid + 256];  // target g = tid+256
#pragma unroll
    for (int b = 1; b < 16; ++b) {
        c0 = fminf(c0, s_col[b * COLSTRIDE + tid]);
        c1 = fminf(c1, s_col[b * COLSTRIDE + tid + 256]);
    }
    double local = (va ? (double)c0 : 0.0) + (vb ? (double)c1 : 0.0);
    unsigned cl = (unsigned)va + (unsigned)vb;

    // ---- block-reduce cham_y partials -------------------------------------
    for (int off = 32; off > 0; off >>= 1) {
        local += __shfl_down(local, off, 64);
        cl    += __shfl_down(cl, off, 64);
    }
    int wave = tid >> 6, lane = tid & 63;
    if (lane == 0) { s_ws[wave] = local; s_wc[wave] = cl; }
    __syncthreads();
    if (tid == 0) {
        double s = s_ws[0] + s_ws[1] + s_ws[2] + s_ws[3];
        unsigned cc = s_wc[0] + s_wc[1] + s_wc[2] + s_wc[3];
        atomicAdd(&ysum[n], s);
        atomicAdd(&ycnt[n], cc);
        __threadfence();
        unsigned old = __hip_atomic_fetch_add(done, 1u, __ATOMIC_ACQ_REL,
                                              __HIP_MEMORY_SCOPE_AGENT);
        s_last = (old == (unsigned)(gridDim.x * gridDim.y - 1));
    }
    __syncthreads();
    if (!s_last) return;

    // ---- last block: finalize ---------------------------------------------
    double part = 0.0;
    for (int nn = 0; nn < N; ++nn) {
        unsigned bbits = __hip_atomic_load(&minbits[nn * P + tid],
                                           __ATOMIC_RELAXED, __HIP_MEMORY_SCOPE_AGENT);
        part += (double)__uint_as_float(bbits);
    }
    for (int off = 32; off > 0; off >>= 1) part += __shfl_down(part, off, 64);
    if (lane == 0) s_ws[wave] = part;
    __syncthreads();
    if (tid == 0) {
        double sx = (s_ws[0] + s_ws[1] + s_ws[2] + s_ws[3]) / (double)P;
        double sy = 0.0;
        for (int nn = 0; nn < N; ++nn) {
            double ys = __hip_atomic_load(&ysum[nn], __ATOMIC_RELAXED,
                                          __HIP_MEMORY_SCOPE_AGENT);
            unsigned yc = __hip_atomic_load(&ycnt[nn], __ATOMIC_RELAXED,
                                            __HIP_MEMORY_SCOPE_AGENT);
            sy += ys / (double)yc;
        }
        out[0] = (float)((sx + sy) / (double)N);
    }
}

extern "C" void kernel_launch(void* const* d_in, const int* in_sizes, int n_in,
                              void* d_out, int out_size, void* d_ws, size_t ws_size,
                              hipStream_t stream) {
    const float* bins = (const float*)d_in[0];
    const float* tgt  = (const float*)d_in[1];
    float* out = (float*)d_out;

    const int N = in_sizes[0] / (P + 1);  // 8
    const int M = in_sizes[1] / N;        // 65536

    char* ws = (char*)d_ws;
    unsigned* done    = (unsigned*)ws;
    double*   ysum    = (double*)(ws + 64);
    unsigned* ycnt    = (unsigned*)(ws + 128);
    unsigned* minbits = (unsigned*)(ws + 192);

    // re-init workspace every call (ws is poisoned 0xAA before each launch)
    hipMemsetAsync(ws, 0x00, 192, stream);                  // done, ysum, ycnt
    hipMemsetAsync(ws + 192, 0xFF, N * P * 4, stream);      // minbits = UINT_MAX

    const int cps = (M + CHUNK - 1) / CHUNK;  // 128 chunks per sample
    hipLaunchKernelGGL(chamfer_main, dim3(cps, N), dim3(BLOCK), 0, stream,
                       bins, tgt, N, M, done, ysum, ycnt, minbits, out);
}

// Round 4
// 148.386 us; speedup vs baseline: 2.6941x; 2.6941x over previous
//
#include <hip/hip_runtime.h>

#define MIN_VAL 1e-8f
#define SENT    1e10f   // sentinel for invalid targets: d ~ 1e20 dominates valid
#define ACCINIT 1e30f

constexpr int P     = 256;   // bins per sample (bins input is [N, P+1])
constexpr int BLOCK = 256;
constexpr int CHUNK = 512;   // targets per block
constexpr int PASS_T = 128;  // targets per pass (16 lanes x 8 targets)
constexpr int COLSTRIDE = CHUNK + 4;  // de-phase bin-group rows across banks

// ---------------------------------------------------------------------------
// ws layout (poisoned 0xAA before every launch; memsets re-init every call):
//   [0,4)    : unsigned done          (memset 0x00)
//   [64,128) : double ysum[8]         (memset 0x00)
//   [128,160): unsigned ycnt[8]       (memset 0x00)
//   [192, 192+N*P*4): unsigned minbits[N*P]  (memset 0xFF = UINT_MAX)
// ---------------------------------------------------------------------------

__global__ void __launch_bounds__(BLOCK, 4)   // cap VGPR at 128: no spills
chamfer_main(const float* __restrict__ bins, const float* __restrict__ tgt,
             int N, int M, unsigned* done, double* ysum, unsigned* ycnt,
             unsigned* minbits, float* out) {
    const int n   = blockIdx.y;
    const int m0  = blockIdx.x * CHUNK;
    const int tid = threadIdx.x;
    const int tg  = tid & 15;   // target-group lane: owns 8 targets per pass
    const int bg  = tid >> 4;   // bin-group: owns bins [bg*16, bg*16+16)

    __shared__ float  s_bc[P];
    __shared__ float  s_t[CHUNK];
    __shared__ float  s_col[16 * COLSTRIDE];  // [bg][target] partial col-mins
    __shared__ double s_ws[BLOCK / 64];
    __shared__ unsigned s_wc[BLOCK / 64];
    __shared__ int s_last;

    // ---- stage bins (thread tid -> bin tid) -------------------------------
    const float* bn = bins + (size_t)n * (P + 1);
    s_bc[tid] = 0.5f * (bn[tid] + bn[tid + 1]);

    // ---- stage targets (thread owns g = tid and g = tid+256) --------------
    const float* tp = tgt + (size_t)n * M + m0;
    float ta = (m0 + tid < M)       ? tp[tid]       : -1.0f;
    float tb = (m0 + tid + 256 < M) ? tp[tid + 256] : -1.0f;
    bool va = ta >= MIN_VAL, vb = tb >= MIN_VAL;
    s_t[tid]       = va ? ta : SENT;
    s_t[tid + 256] = vb ? tb : SENT;
    __syncthreads();

    // ---- persistent register state: 16 bins + 16 row-mins = 32 floats -----
    float bcv[16];
#pragma unroll
    for (int i = 0; i < 16; i += 4) {
        float4 v = *(const float4*)&s_bc[bg * 16 + i];
        bcv[i] = v.x; bcv[i + 1] = v.y; bcv[i + 2] = v.z; bcv[i + 3] = v.w;
    }
    float rmin[16];
#pragma unroll
    for (int i = 0; i < 16; ++i) rmin[i] = ACCINIT;

    // ---- 4 passes of 16 bins x 8 targets per thread -----------------------
#pragma unroll 1   // keep per-pass temporaries from multiplying (spill guard)
    for (int pass = 0; pass < CHUNK / PASS_T; ++pass) {
        const int base = pass * PASS_T + tg * 8;
        float4 t4a = *(const float4*)&s_t[base];
        float4 t4b = *(const float4*)&s_t[base + 4];
        float tv[8] = {t4a.x, t4a.y, t4a.z, t4a.w, t4b.x, t4b.y, t4b.z, t4b.w};
        float cmin[8];
#pragma unroll
        for (int j = 0; j < 8; ++j) cmin[j] = ACCINIT;
#pragma unroll
        for (int j = 0; j < 8; ++j) {
            float t = tv[j];
            float cm = cmin[j];
#pragma unroll
            for (int i = 0; i < 16; ++i) {
                float d = bcv[i] - t;
                d = d * d;
                rmin[i] = fminf(rmin[i], d);
                cm = fminf(cm, d);
            }
            cmin[j] = cm;
        }
        float* cp = &s_col[bg * COLSTRIDE + base];
        *(float4*)cp       = make_float4(cmin[0], cmin[1], cmin[2], cmin[3]);
        *(float4*)(cp + 4) = make_float4(cmin[4], cmin[5], cmin[6], cmin[7]);
    }

    // ---- row (per-bin) combine: shfl across the 16-lane target-group ------
#pragma unroll
    for (int i = 0; i < 16; ++i) {
        float r = rmin[i];
        r = fminf(r, __shfl_down(r, 8, 16));
        r = fminf(r, __shfl_down(r, 4, 16));
        r = fminf(r, __shfl_down(r, 2, 16));
        r = fminf(r, __shfl_down(r, 1, 16));
        rmin[i] = r;
    }
    if (tg == 0) {
#pragma unroll
        for (int i = 0; i < 16; ++i)
            atomicMin(&minbits[n * P + bg * 16 + i], __float_as_uint(rmin[i]));
    }

    // ---- col (per-target) combine via LDS ---------------------------------
    __syncthreads();
    float c0 = s_col[tid];        // target g = tid
    float c1 = s_col[tid + 256];  // target g = tid+256
#pragma unroll
    for (int b = 1; b < 16; ++b) {
        c0 = fminf(c0, s_col[b * COLSTRIDE + tid]);
        c1 = fminf(c1, s_col[b * COLSTRIDE + tid + 256]);
    }
    double local = (va ? (double)c0 : 0.0) + (vb ? (double)c1 : 0.0);
    unsigned cl = (unsigned)va + (unsigned)vb;

    // ---- block-reduce cham_y partials -------------------------------------
    for (int off = 32; off > 0; off >>= 1) {
        local += __shfl_down(local, off, 64);
        cl    += __shfl_down(cl, off, 64);
    }
    int wave = tid >> 6, lane = tid & 63;
    if (lane == 0) { s_ws[wave] = local; s_wc[wave] = cl; }
    __syncthreads();
    if (tid == 0) {
        double s = s_ws[0] + s_ws[1] + s_ws[2] + s_ws[3];
        unsigned cc = s_wc[0] + s_wc[1] + s_wc[2] + s_wc[3];
        atomicAdd(&ysum[n], s);
        atomicAdd(&ycnt[n], cc);
        __threadfence();
        unsigned old = __hip_atomic_fetch_add(done, 1u, __ATOMIC_ACQ_REL,
                                              __HIP_MEMORY_SCOPE_AGENT);
        s_last = (old == (unsigned)(gridDim.x * gridDim.y - 1));
    }
    __syncthreads();
    if (!s_last) return;

    // ---- last block: finalize ---------------------------------------------
    double part = 0.0;
    for (int nn = 0; nn < N; ++nn) {
        unsigned bbits = __hip_atomic_load(&minbits[nn * P + tid],
                                           __ATOMIC_RELAXED, __HIP_MEMORY_SCOPE_AGENT);
        part += (double)__uint_as_float(bbits);
    }
    for (int off = 32; off > 0; off >>= 1) part += __shfl_down(part, off, 64);
    if (lane == 0) s_ws[wave] = part;
    __syncthreads();
    if (tid == 0) {
        double sx = (s_ws[0] + s_ws[1] + s_ws[2] + s_ws[3]) / (double)P;
        double sy = 0.0;
        for (int nn = 0; nn < N; ++nn) {
            double ys = __hip_atomic_load(&ysum[nn], __ATOMIC_RELAXED,
                                          __HIP_MEMORY_SCOPE_AGENT);
            unsigned yc = __hip_atomic_load(&ycnt[nn], __ATOMIC_RELAXED,
                                            __HIP_MEMORY_SCOPE_AGENT);
            sy += ys / (double)yc;
        }
        out[0] = (float)((sx + sy) / (double)N);
    }
}

extern "C" void kernel_launch(void* const* d_in, const int* in_sizes, int n_in,
                              void* d_out, int out_size, void* d_ws, size_t ws_size,
                              hipStream_t stream) {
    const float* bins = (const float*)d_in[0];
    const float* tgt  = (const float*)d_in[1];
    float* out = (float*)d_out;

    const int N = in_sizes[0] / (P + 1);  // 8
    const int M = in_sizes[1] / N;        // 65536

    char* ws = (char*)d_ws;
    unsigned* done    = (unsigned*)ws;
    double*   ysum    = (double*)(ws + 64);
    unsigned* ycnt    = (unsigned*)(ws + 128);
    unsigned* minbits = (unsigned*)(ws + 192);

    // re-init workspace every call (ws is poisoned 0xAA before each launch)
    hipMemsetAsync(ws, 0x00, 192, stream);              // done, ysum, ycnt
    hipMemsetAsync(ws + 192, 0xFF, N * P * 4, stream);  // minbits = UINT_MAX

    const int cps = (M + CHUNK - 1) / CHUNK;  // 128 chunks per sample
    hipLaunchKernelGGL(chamfer_main, dim3(cps, N), dim3(BLOCK), 0, stream,
                       bins, tgt, N, M, done, ysum, ycnt, minbits, out);
}